// Round 1
// baseline (431.511 us; speedup 1.0000x reference)
//
#include <hip/hip_runtime.h>
#include <hip/hip_bf16.h>
#include <math.h>

// Problem constants (B=1)
constexpr int S  = 2048;
constexpr int D  = 1024;
constexpr int H  = 16;
constexpr int HD = 64;
constexpr int FF = 4096;
constexpr int NC  = 32;   // number of chunks for linear attention
constexpr int CHK = 64;   // chunk length (timesteps)

typedef __attribute__((ext_vector_type(8))) short bf16x8;
typedef __attribute__((ext_vector_type(4))) float f32x4;

__device__ inline unsigned short f2bf(float f) {
    unsigned int u = __float_as_uint(f);
    u = (u + 0x7FFFu + ((u >> 16) & 1u)) >> 16;   // RNE
    return (unsigned short)u;
}

// ---------------- fp32 -> bf16 convert (weights / activations) ----------------
__global__ __launch_bounds__(256) void cvt_bf16(const float* __restrict__ src,
                                                unsigned short* __restrict__ dst,
                                                int n4) {
    int i = blockIdx.x * 256 + threadIdx.x;
    if (i >= n4) return;
    float4 v = ((const float4*)src)[i];
    ushort4 o = { f2bf(v.x), f2bf(v.y), f2bf(v.z), f2bf(v.w) };
    ((ushort4*)dst)[i] = o;
}

// ---------------- LayerNorm (fp32 in, bf16 out), one block per row ----------------
__global__ __launch_bounds__(256) void layernorm_bf16(const float* __restrict__ x,
                                                      const float* __restrict__ g,
                                                      const float* __restrict__ b,
                                                      unsigned short* __restrict__ out) {
    const int row = blockIdx.x, tid = threadIdx.x;
    float4 v = ((const float4*)(x + (size_t)row * D))[tid];
    float s  = v.x + v.y + v.z + v.w;
    float ss = v.x*v.x + v.y*v.y + v.z*v.z + v.w*v.w;
    #pragma unroll
    for (int off = 32; off > 0; off >>= 1) {
        s  += __shfl_down(s, off);
        ss += __shfl_down(ss, off);
    }
    __shared__ float sw[4], ssw[4];
    if ((tid & 63) == 0) { sw[tid >> 6] = s; ssw[tid >> 6] = ss; }
    __syncthreads();
    s  = sw[0] + sw[1] + sw[2] + sw[3];
    ss = ssw[0] + ssw[1] + ssw[2] + ssw[3];
    const float mu = s * (1.0f / D);
    const float rs = rsqrtf(ss * (1.0f / D) - mu * mu + 1e-5f);
    float4 gv = ((const float4*)g)[tid];
    float4 bv = ((const float4*)b)[tid];
    ushort4 o = { f2bf((v.x - mu) * rs * gv.x + bv.x),
                  f2bf((v.y - mu) * rs * gv.y + bv.y),
                  f2bf((v.z - mu) * rs * gv.z + bv.z),
                  f2bf((v.w - mu) * rs * gv.w + bv.w) };
    ((ushort4*)(out + (size_t)row * D))[tid] = o;
}

// ---------------- bf16 MFMA GEMM: C = A (MxK) * W^T (W is NxK) + bias, epilogues ----------------
// 128x128 tile, BK=32, 256 threads (4 waves, 2x2 of 64x64), 16x16x32 MFMA.
enum { EPI_F32 = 0, EPI_ELU1 = 1, EPI_GELU_BF16 = 2, EPI_RES_F32 = 3 };

template <int EPI>
__global__ __launch_bounds__(256) void gemm_bt(const unsigned short* __restrict__ A,
                                               const unsigned short* __restrict__ W,
                                               const float* __restrict__ bias,
                                               const float* __restrict__ res,
                                               void* __restrict__ outp,
                                               int M, int N, int K) {
    __shared__ unsigned short As[128 * 40];   // stride 40 elems (80B): 2-way LDS banking only
    __shared__ unsigned short Bs[128 * 40];
    const int tid  = threadIdx.x;
    const int tileM = blockIdx.x * 128;
    const int tileN = blockIdx.y * 128;
    const int w    = tid >> 6, lane = tid & 63;
    const int wm   = (w >> 1) * 64, wn = (w & 1) * 64;
    const int lr   = lane & 15, lk = lane >> 4;

    f32x4 acc[4][4];
    #pragma unroll
    for (int i = 0; i < 4; ++i)
        #pragma unroll
        for (int j = 0; j < 4; ++j) acc[i][j] = (f32x4)(0.0f);

    for (int k0 = 0; k0 < K; k0 += 32) {
        #pragma unroll
        for (int p = 0; p < 2; ++p) {
            int c   = p * 256 + tid;            // 512 chunks of 8 bf16 (16B)
            int row = c >> 2, kc = (c & 3) * 8;
            uint4 av = *(const uint4*)(A + (size_t)(tileM + row) * K + k0 + kc);
            uint4 bv = *(const uint4*)(W + (size_t)(tileN + row) * K + k0 + kc);
            *(uint4*)(&As[row * 40 + kc]) = av;
            *(uint4*)(&Bs[row * 40 + kc]) = bv;
        }
        __syncthreads();
        bf16x8 af[4], bfv[4];
        #pragma unroll
        for (int i = 0; i < 4; ++i) {
            af[i]  = *(const bf16x8*)&As[(wm + i * 16 + lr) * 40 + lk * 8];
            bfv[i] = *(const bf16x8*)&Bs[(wn + i * 16 + lr) * 40 + lk * 8];
        }
        #pragma unroll
        for (int i = 0; i < 4; ++i)
            #pragma unroll
            for (int j = 0; j < 4; ++j)
                acc[i][j] = __builtin_amdgcn_mfma_f32_16x16x32_bf16(af[i], bfv[j], acc[i][j], 0, 0, 0);
        __syncthreads();
    }

    // Epilogue. C/D layout: col = lane&15, row = (lane>>4)*4 + reg   [m89/m91-verified]
    #pragma unroll
    for (int i = 0; i < 4; ++i) {
        const int rbase = tileM + wm + i * 16 + lk * 4;
        #pragma unroll
        for (int j = 0; j < 4; ++j) {
            const int col = tileN + wn + j * 16 + lr;
            const float bcol = bias[col];
            #pragma unroll
            for (int r = 0; r < 4; ++r) {
                const int row = rbase + r;
                float v = acc[i][j][r] + bcol;
                const size_t off = (size_t)row * N + col;
                if constexpr (EPI == EPI_ELU1) {
                    v = v > 0.0f ? v + 1.0f : __expf(v);      // elu(v)+1
                    ((float*)outp)[off] = v;
                } else if constexpr (EPI == EPI_GELU_BF16) {
                    float gl = 0.5f * v * (1.0f + erff(v * 0.70710678118654752f));
                    ((unsigned short*)outp)[off] = f2bf(gl);
                } else if constexpr (EPI == EPI_RES_F32) {
                    ((float*)outp)[off] = v + res[off];
                } else {
                    ((float*)outp)[off] = v;
                }
            }
        }
    }
}

// ---------------- linear attention, chunked causal scan (fp32) ----------------
// Kernel A: per (chunk, head) sums: KVc[h][c][d][e] = sum_t k[t][d] v[t][e]; Zc = sum_t k[t][d]
__global__ __launch_bounds__(256) void attn_chunk_sums(const float* __restrict__ kbuf,
                                                       const float* __restrict__ vbuf,
                                                       float* __restrict__ KVc,
                                                       float* __restrict__ Zc) {
    const int c = blockIdx.x, h = blockIdx.y, tid = threadIdx.x;
    __shared__ float Kc[CHK * HD], Vc[CHK * HD];
    const int s0 = c * CHK;
    #pragma unroll
    for (int p = 0; p < 4; ++p) {
        int cc = p * 256 + tid;                 // 1024 float4 chunks
        int t = cc >> 4, dp = (cc & 15) * 4;
        *(float4*)&Kc[t * HD + dp] = *(const float4*)(kbuf + (size_t)(s0 + t) * D + h * HD + dp);
        *(float4*)&Vc[t * HD + dp] = *(const float4*)(vbuf + (size_t)(s0 + t) * D + h * HD + dp);
    }
    __syncthreads();
    const int d = tid >> 2, e0 = (tid & 3) * 16;
    float acc[16];
    #pragma unroll
    for (int j = 0; j < 16; ++j) acc[j] = 0.0f;
    float zacc = 0.0f;
    for (int t = 0; t < CHK; ++t) {
        float kv = Kc[t * HD + d];
        zacc += kv;
        #pragma unroll
        for (int j = 0; j < 16; ++j) acc[j] += kv * Vc[t * HD + e0 + j];
    }
    float* op = KVc + ((size_t)(h * NC + c) * HD + d) * HD + e0;
    #pragma unroll
    for (int j = 0; j < 16; ++j) op[j] = acc[j];
    if ((tid & 3) == 0) Zc[(size_t)(h * NC + c) * HD + d] = zacc;
}

// Kernel B: exclusive prefix over chunks (per head). grid (16 segs, H)
__global__ __launch_bounds__(256) void attn_prefix(const float* __restrict__ KVc,
                                                   float* __restrict__ KVpre,
                                                   const float* __restrict__ Zc,
                                                   float* __restrict__ Zpre) {
    const int h = blockIdx.y;
    const int elem = blockIdx.x * 256 + threadIdx.x;      // 0..4095
    size_t base = (size_t)h * NC * (HD * HD) + elem;
    float run = 0.0f;
    for (int c = 0; c < NC; ++c) {
        float t = KVc[base + (size_t)c * (HD * HD)];
        KVpre[base + (size_t)c * (HD * HD)] = run;
        run += t;
    }
    if (blockIdx.x == 0 && threadIdx.x < HD) {
        size_t zb = (size_t)h * NC * HD + threadIdx.x;
        float zr = 0.0f;
        for (int c = 0; c < NC; ++c) {
            float t = Zc[zb + (size_t)c * HD];
            Zpre[zb + (size_t)c * HD] = zr;
            zr += t;
        }
    }
}

// Kernel C: per (chunk, head) output: out = (Q*KVpre + tril(QK^T)*V) / (Q.zpre + rowsum + eps)
__global__ __launch_bounds__(256) void attn_out(const float* __restrict__ qbuf,
                                                const float* __restrict__ kbuf,
                                                const float* __restrict__ vbuf,
                                                const float* __restrict__ KVpre,
                                                const float* __restrict__ Zpre,
                                                unsigned short* __restrict__ attn) {
    const int c = blockIdx.x, h = blockIdx.y, tid = threadIdx.x;
    __shared__ float Qc[CHK * HD], KVs[CHK * HD], Pre[HD * HD], Sc[CHK * CHK];
    __shared__ float zp[HD], den[CHK];
    const int s0 = c * CHK;
    #pragma unroll
    for (int p = 0; p < 4; ++p) {
        int cc = p * 256 + tid;
        int t = cc >> 4, dp = (cc & 15) * 4;
        *(float4*)&Qc[t * HD + dp]  = *(const float4*)(qbuf + (size_t)(s0 + t) * D + h * HD + dp);
        *(float4*)&KVs[t * HD + dp] = *(const float4*)(kbuf + (size_t)(s0 + t) * D + h * HD + dp);
        ((float4*)Pre)[cc] = *(const float4*)(KVpre + (size_t)(h * NC + c) * (HD * HD) + cc * 4);
    }
    if (tid < HD) zp[tid] = Zpre[(size_t)(h * NC + c) * HD + tid];
    __syncthreads();

    const int tt = tid >> 2, i0 = (tid & 3) * 16;
    // scores (masked)
    for (int i = i0; i < i0 + 16; ++i) {
        float sv = 0.0f;
        for (int d2 = 0; d2 < HD; ++d2) sv += Qc[tt * HD + d2] * KVs[i * HD + d2];
        Sc[tt * CHK + i] = (i <= tt) ? sv : 0.0f;
    }
    __syncthreads();   // K fully consumed; Sc visible

    // den, and reload KVs with V
    if (tid < CHK) {
        float dv = 1e-6f;
        for (int d2 = 0; d2 < HD; ++d2) dv += Qc[tid * HD + d2] * zp[d2];
        for (int i = 0; i < CHK; ++i) dv += Sc[tid * CHK + i];   // masked entries are 0
        den[tid] = dv;
    }
    #pragma unroll
    for (int p = 0; p < 4; ++p) {
        int cc = p * 256 + tid;
        int t = cc >> 4, dp = (cc & 15) * 4;
        *(float4*)&KVs[t * HD + dp] = *(const float4*)(vbuf + (size_t)(s0 + t) * D + h * HD + dp);
    }
    __syncthreads();

    float o[16];
    #pragma unroll
    for (int j = 0; j < 16; ++j) o[j] = 0.0f;
    for (int d2 = 0; d2 < HD; ++d2) {
        float qv = Qc[tt * HD + d2];
        float sv = Sc[tt * CHK + d2];
        #pragma unroll
        for (int j = 0; j < 16; ++j)
            o[j] += qv * Pre[d2 * HD + i0 + j] + sv * KVs[d2 * HD + i0 + j];
    }
    const float inv = 1.0f / den[tt];
    unsigned short* op = attn + (size_t)(s0 + tt) * D + h * HD + i0;
    #pragma unroll
    for (int j0 = 0; j0 < 16; j0 += 4) {
        ushort4 ov = { f2bf(o[j0] * inv), f2bf(o[j0 + 1] * inv),
                       f2bf(o[j0 + 2] * inv), f2bf(o[j0 + 3] * inv) };
        *(ushort4*)(op + j0) = ov;
    }
}

// ---------------- launcher ----------------
extern "C" void kernel_launch(void* const* d_in, const int* in_sizes, int n_in,
                              void* d_out, int out_size, void* d_ws, size_t ws_size,
                              hipStream_t stream) {
    const float* x   = (const float*)d_in[0];
    const float* Wq  = (const float*)d_in[1];
    const float* bq  = (const float*)d_in[2];
    const float* Wk  = (const float*)d_in[3];
    const float* bk  = (const float*)d_in[4];
    const float* Wv  = (const float*)d_in[5];
    const float* bv  = (const float*)d_in[6];
    const float* Wo  = (const float*)d_in[7];
    const float* bo  = (const float*)d_in[8];
    const float* W1  = (const float*)d_in[9];
    const float* b1  = (const float*)d_in[10];
    const float* W2  = (const float*)d_in[11];
    const float* b2  = (const float*)d_in[12];
    const float* g1  = (const float*)d_in[13];
    const float* be1 = (const float*)d_in[14];
    const float* g2  = (const float*)d_in[15];
    const float* be2 = (const float*)d_in[16];
    float* out = (float*)d_out;

    char* wsp = (char*)d_ws;
    auto alloc = [&](size_t bytes) {
        char* p = wsp;
        wsp += (bytes + 255) & ~(size_t)255;
        return p;
    };
    unsigned short* h1   = (unsigned short*)alloc((size_t)S * D * 2);
    unsigned short* h2   = (unsigned short*)alloc((size_t)S * D * 2);
    unsigned short* attn = (unsigned short*)alloc((size_t)S * D * 2);
    unsigned short* gbuf = (unsigned short*)alloc((size_t)S * FF * 2);
    float* qb   = (float*)alloc((size_t)S * D * 4);
    float* kb   = (float*)alloc((size_t)S * D * 4);
    float* vb   = (float*)alloc((size_t)S * D * 4);
    float* x2   = (float*)alloc((size_t)S * D * 4);
    unsigned short* Wqb = (unsigned short*)alloc((size_t)D * D * 2);
    unsigned short* Wkb = (unsigned short*)alloc((size_t)D * D * 2);
    unsigned short* Wvb = (unsigned short*)alloc((size_t)D * D * 2);
    unsigned short* Wob = (unsigned short*)alloc((size_t)D * D * 2);
    unsigned short* W1b = (unsigned short*)alloc((size_t)FF * D * 2);
    unsigned short* W2b = (unsigned short*)alloc((size_t)D * FF * 2);
    float* KVc   = (float*)alloc((size_t)H * NC * HD * HD * 4);
    float* KVpre = (float*)alloc((size_t)H * NC * HD * HD * 4);
    float* Zc    = (float*)alloc((size_t)H * NC * HD * 4);
    float* Zpre  = (float*)alloc((size_t)H * NC * HD * 4);

    const int DD4 = D * D / 4, FD4 = FF * D / 4;
    cvt_bf16<<<DD4 / 256, 256, 0, stream>>>(Wq, Wqb, DD4);
    cvt_bf16<<<DD4 / 256, 256, 0, stream>>>(Wk, Wkb, DD4);
    cvt_bf16<<<DD4 / 256, 256, 0, stream>>>(Wv, Wvb, DD4);
    cvt_bf16<<<DD4 / 256, 256, 0, stream>>>(Wo, Wob, DD4);
    cvt_bf16<<<FD4 / 256, 256, 0, stream>>>(W1, W1b, FD4);
    cvt_bf16<<<FD4 / 256, 256, 0, stream>>>(W2, W2b, FD4);

    // LN1
    layernorm_bf16<<<S, 256, 0, stream>>>(x, g1, be1, h1);

    // QKV projections (elu+1 fused for q,k)
    dim3 gqkv(S / 128, D / 128);
    gemm_bt<EPI_ELU1><<<gqkv, 256, 0, stream>>>(h1, Wqb, bq, nullptr, qb, S, D, D);
    gemm_bt<EPI_ELU1><<<gqkv, 256, 0, stream>>>(h1, Wkb, bk, nullptr, kb, S, D, D);
    gemm_bt<EPI_F32 ><<<gqkv, 256, 0, stream>>>(h1, Wvb, bv, nullptr, vb, S, D, D);

    // chunked causal linear attention
    attn_chunk_sums<<<dim3(NC, H), 256, 0, stream>>>(kb, vb, KVc, Zc);
    attn_prefix<<<dim3(16, H), 256, 0, stream>>>(KVc, KVpre, Zc, Zpre);
    attn_out<<<dim3(NC, H), 256, 0, stream>>>(qb, kb, vb, KVpre, Zpre, attn);

    // out-proj + residual -> x2
    gemm_bt<EPI_RES_F32><<<gqkv, 256, 0, stream>>>(attn, Wob, bo, x, x2, S, D, D);

    // LN2
    layernorm_bf16<<<S, 256, 0, stream>>>(x2, g2, be2, h2);

    // FFN
    dim3 gff1(S / 128, FF / 128);
    gemm_bt<EPI_GELU_BF16><<<gff1, 256, 0, stream>>>(h2, W1b, b1, nullptr, gbuf, S, FF, D);
    dim3 gff2(S / 128, D / 128);
    gemm_bt<EPI_RES_F32><<<gff2, 256, 0, stream>>>(gbuf, W2b, b2, x2, out, S, D, FF);
}

// Round 2
// 319.475 us; speedup vs baseline: 1.3507x; 1.3507x over previous
//
#include <hip/hip_runtime.h>
#include <hip/hip_bf16.h>
#include <math.h>

// Problem constants (B=1)
constexpr int S  = 2048;
constexpr int D  = 1024;
constexpr int H  = 16;
constexpr int HD = 64;
constexpr int FF = 4096;
constexpr int NC  = 32;   // number of chunks for linear attention
constexpr int CHK = 64;   // chunk length (timesteps)
constexpr int QS  = 3 * D; // fused qkv row stride

typedef __attribute__((ext_vector_type(8))) short bf16x8;
typedef __attribute__((ext_vector_type(4))) float f32x4;

__device__ inline unsigned short f2bf(float f) {
    unsigned int u = __float_as_uint(f);
    u = (u + 0x7FFFu + ((u >> 16) & 1u)) >> 16;   // RNE
    return (unsigned short)u;
}

// ---------------- fp32 -> bf16 convert (weights) ----------------
__global__ __launch_bounds__(256) void cvt_bf16(const float* __restrict__ src,
                                                unsigned short* __restrict__ dst,
                                                int n4) {
    int i = blockIdx.x * 256 + threadIdx.x;
    if (i >= n4) return;
    float4 v = ((const float4*)src)[i];
    ushort4 o = { f2bf(v.x), f2bf(v.y), f2bf(v.z), f2bf(v.w) };
    ((ushort4*)dst)[i] = o;
}

// concat 3 bias vectors (fp32) into one 3*D vector
__global__ __launch_bounds__(256) void concat3(const float* __restrict__ a,
                                               const float* __restrict__ b,
                                               const float* __restrict__ c,
                                               float* __restrict__ o) {
    int i = blockIdx.x * 256 + threadIdx.x;
    if (i >= 3 * D) return;
    const float* s = (i < D) ? a : ((i < 2 * D) ? b : c);
    o[i] = s[i & (D - 1)];
}

// ---------------- LayerNorm (fp32 in, bf16 out), one block per row ----------------
__global__ __launch_bounds__(256) void layernorm_bf16(const float* __restrict__ x,
                                                      const float* __restrict__ g,
                                                      const float* __restrict__ b,
                                                      unsigned short* __restrict__ out) {
    const int row = blockIdx.x, tid = threadIdx.x;
    float4 v = ((const float4*)(x + (size_t)row * D))[tid];
    float s  = v.x + v.y + v.z + v.w;
    float ss = v.x*v.x + v.y*v.y + v.z*v.z + v.w*v.w;
    #pragma unroll
    for (int off = 32; off > 0; off >>= 1) {
        s  += __shfl_down(s, off);
        ss += __shfl_down(ss, off);
    }
    __shared__ float sw[4], ssw[4];
    if ((tid & 63) == 0) { sw[tid >> 6] = s; ssw[tid >> 6] = ss; }
    __syncthreads();
    s  = sw[0] + sw[1] + sw[2] + sw[3];
    ss = ssw[0] + ssw[1] + ssw[2] + ssw[3];
    const float mu = s * (1.0f / D);
    const float rs = rsqrtf(ss * (1.0f / D) - mu * mu + 1e-5f);
    float4 gv = ((const float4*)g)[tid];
    float4 bv = ((const float4*)b)[tid];
    ushort4 o = { f2bf((v.x - mu) * rs * gv.x + bv.x),
                  f2bf((v.y - mu) * rs * gv.y + bv.y),
                  f2bf((v.z - mu) * rs * gv.z + bv.z),
                  f2bf((v.w - mu) * rs * gv.w + bv.w) };
    ((ushort4*)(out + (size_t)row * D))[tid] = o;
}

// ---------------- bf16 MFMA GEMM: C = A (MxK) * W^T (W is NxK), m97-style staging ----------------
// 128x128 tile, BK=32, 256 threads (4 waves, 2x2 of 64x64), 16x16x32 MFMA.
// Staging via global_load_lds width=16: LDS layout MUST be contiguous in lane order
// (stride 32 elems, no padding) per the wave-uniform-base rule.
enum { EPI_F32 = 0, EPI_QKV = 1, EPI_GELU_BF16 = 2, EPI_PART = 3 };

template <int EPI>
__global__ __launch_bounds__(256) void gemm_bt(const unsigned short* __restrict__ A,
                                               const unsigned short* __restrict__ W,
                                               const float* __restrict__ bias,
                                               void* __restrict__ outp,
                                               int M, int N, int K, int kSplit) {
    __shared__ unsigned short As[128 * 32];
    __shared__ unsigned short Bs[128 * 32];
    const int tid  = threadIdx.x;
    const int tileM = blockIdx.x * 128;
    const int tileN = blockIdx.y * 128;
    const int w    = tid >> 6, lane = tid & 63;
    const int wm   = (w >> 1) * 64, wn = (w & 1) * 64;
    const int lr   = lane & 15, lk = lane >> 4;
    const int kLen   = K / kSplit;
    const int kStart = blockIdx.z * kLen;
    const int kEnd   = kStart + kLen;

    f32x4 acc[4][4];
    #pragma unroll
    for (int i = 0; i < 4; ++i)
        #pragma unroll
        for (int j = 0; j < 4; ++j) acc[i][j] = (f32x4)(0.0f);

    for (int k0 = kStart; k0 < kEnd; k0 += 32) {
        #pragma unroll
        for (int p = 0; p < 2; ++p) {
            const int c   = p * 256 + tid;       // 512 chunks of 16B per tile
            const int row = c >> 2, kc = (c & 3) * 8;
            __builtin_amdgcn_global_load_lds(
                (const __attribute__((address_space(1))) unsigned int*)
                    (A + (size_t)(tileM + row) * K + k0 + kc),
                (__attribute__((address_space(3))) unsigned int*)&As[c * 8],
                16, 0, 0);
            __builtin_amdgcn_global_load_lds(
                (const __attribute__((address_space(1))) unsigned int*)
                    (W + (size_t)(tileN + row) * K + k0 + kc),
                (__attribute__((address_space(3))) unsigned int*)&Bs[c * 8],
                16, 0, 0);
        }
        __syncthreads();
        bf16x8 af[4], bfv[4];
        #pragma unroll
        for (int i = 0; i < 4; ++i) {
            af[i]  = *(const bf16x8*)&As[(wm + i * 16 + lr) * 32 + lk * 8];
            bfv[i] = *(const bf16x8*)&Bs[(wn + i * 16 + lr) * 32 + lk * 8];
        }
        #pragma unroll
        for (int i = 0; i < 4; ++i)
            #pragma unroll
            for (int j = 0; j < 4; ++j)
                acc[i][j] = __builtin_amdgcn_mfma_f32_16x16x32_bf16(af[i], bfv[j], acc[i][j], 0, 0, 0);
        __syncthreads();
    }

    // Epilogue. C/D layout: col = lane&15, row = (lane>>4)*4 + reg   [m89/m91-verified]
    #pragma unroll
    for (int i = 0; i < 4; ++i) {
        const int rbase = tileM + wm + i * 16 + lk * 4;
        #pragma unroll
        for (int j = 0; j < 4; ++j) {
            const int col = tileN + wn + j * 16 + lr;
            #pragma unroll
            for (int r = 0; r < 4; ++r) {
                const int row = rbase + r;
                const size_t off = (size_t)row * N + col;
                float v = acc[i][j][r];
                if constexpr (EPI == EPI_PART) {
                    // raw split-K partial, no bias
                    ((float*)outp)[(size_t)blockIdx.z * (size_t)M * (size_t)N + off] = v;
                } else if constexpr (EPI == EPI_QKV) {
                    v += bias[col];
                    if (col < 2 * D) v = v > 0.0f ? v + 1.0f : __expf(v);  // elu+1 for q,k
                    ((float*)outp)[off] = v;
                } else if constexpr (EPI == EPI_GELU_BF16) {
                    v += bias[col];
                    float gl = 0.5f * v * (1.0f + erff(v * 0.70710678118654752f));
                    ((unsigned short*)outp)[off] = f2bf(gl);
                } else {
                    v += bias[col];
                    ((float*)outp)[off] = v;
                }
            }
        }
    }
}

// ---------------- split-K reduce: out = sum_z part[z] + bias[col] + res ----------------
__global__ __launch_bounds__(256) void reduce_bias_res(const float* __restrict__ part,
                                                       const float* __restrict__ bias,
                                                       const float* __restrict__ res,
                                                       float* __restrict__ out,
                                                       int N4, int total4, int KS) {
    int i = blockIdx.x * 256 + threadIdx.x;
    if (i >= total4) return;
    float4 a = ((const float4*)part)[i];
    for (int z = 1; z < KS; ++z) {
        float4 p = ((const float4*)part)[(size_t)z * total4 + i];
        a.x += p.x; a.y += p.y; a.z += p.z; a.w += p.w;
    }
    float4 b = ((const float4*)bias)[i % N4];
    float4 r = ((const float4*)res)[i];
    a.x += b.x + r.x; a.y += b.y + r.y; a.z += b.z + r.z; a.w += b.w + r.w;
    ((float4*)out)[i] = a;
}

// ---------------- linear attention, chunked causal scan (fp32) ----------------
// qkv buffer layout: row s = [q(D) | k(D) | v(D)], stride QS=3*D.
__global__ __launch_bounds__(256) void attn_chunk_sums(const float* __restrict__ qkv,
                                                       float* __restrict__ KVc,
                                                       float* __restrict__ Zc) {
    const int c = blockIdx.x, h = blockIdx.y, tid = threadIdx.x;
    __shared__ float Kc[CHK * HD], Vc[CHK * HD];
    const int s0 = c * CHK;
    #pragma unroll
    for (int p = 0; p < 4; ++p) {
        int cc = p * 256 + tid;                 // 1024 float4 chunks
        int t = cc >> 4, dp = (cc & 15) * 4;
        *(float4*)&Kc[t * HD + dp] = *(const float4*)(qkv + (size_t)(s0 + t) * QS + D     + h * HD + dp);
        *(float4*)&Vc[t * HD + dp] = *(const float4*)(qkv + (size_t)(s0 + t) * QS + 2 * D + h * HD + dp);
    }
    __syncthreads();
    const int d = tid >> 2, e0 = (tid & 3) * 16;
    float acc[16];
    #pragma unroll
    for (int j = 0; j < 16; ++j) acc[j] = 0.0f;
    float zacc = 0.0f;
    for (int t = 0; t < CHK; ++t) {
        float kv = Kc[t * HD + d];
        zacc += kv;
        #pragma unroll
        for (int j = 0; j < 16; ++j) acc[j] += kv * Vc[t * HD + e0 + j];
    }
    float* op = KVc + ((size_t)(h * NC + c) * HD + d) * HD + e0;
    #pragma unroll
    for (int j = 0; j < 16; ++j) op[j] = acc[j];
    if ((tid & 3) == 0) Zc[(size_t)(h * NC + c) * HD + d] = zacc;
}

// exclusive prefix over chunks (per head), IN-PLACE safe (per-element chain)
__global__ __launch_bounds__(256) void attn_prefix(float* __restrict__ KVc,
                                                   float* __restrict__ Zc) {
    const int h = blockIdx.y;
    const int elem = blockIdx.x * 256 + threadIdx.x;      // 0..4095
    size_t base = (size_t)h * NC * (HD * HD) + elem;
    float run = 0.0f;
    for (int c = 0; c < NC; ++c) {
        float t = KVc[base + (size_t)c * (HD * HD)];
        KVc[base + (size_t)c * (HD * HD)] = run;
        run += t;
    }
    if (blockIdx.x == 0 && threadIdx.x < HD) {
        size_t zb = (size_t)h * NC * HD + threadIdx.x;
        float zr = 0.0f;
        for (int c = 0; c < NC; ++c) {
            float t = Zc[zb + (size_t)c * HD];
            Zc[zb + (size_t)c * HD] = zr;
            zr += t;
        }
    }
}

// out = (Q*KVpre + tril(QK^T)*V) / (Q.zpre + rowsum + eps)
__global__ __launch_bounds__(256) void attn_out(const float* __restrict__ qkv,
                                                const float* __restrict__ KVpre,
                                                const float* __restrict__ Zpre,
                                                unsigned short* __restrict__ attn) {
    const int c = blockIdx.x, h = blockIdx.y, tid = threadIdx.x;
    __shared__ float Qc[CHK * HD], KVs[CHK * HD], Pre[HD * HD], Sc[CHK * CHK];
    __shared__ float zp[HD], den[CHK];
    const int s0 = c * CHK;
    #pragma unroll
    for (int p = 0; p < 4; ++p) {
        int cc = p * 256 + tid;
        int t = cc >> 4, dp = (cc & 15) * 4;
        *(float4*)&Qc[t * HD + dp]  = *(const float4*)(qkv + (size_t)(s0 + t) * QS +     h * HD + dp);
        *(float4*)&KVs[t * HD + dp] = *(const float4*)(qkv + (size_t)(s0 + t) * QS + D + h * HD + dp);
        ((float4*)Pre)[cc] = *(const float4*)(KVpre + (size_t)(h * NC + c) * (HD * HD) + cc * 4);
    }
    if (tid < HD) zp[tid] = Zpre[(size_t)(h * NC + c) * HD + tid];
    __syncthreads();

    const int tt = tid >> 2, i0 = (tid & 3) * 16;
    // scores (masked)
    for (int i = i0; i < i0 + 16; ++i) {
        float sv = 0.0f;
        for (int d2 = 0; d2 < HD; ++d2) sv += Qc[tt * HD + d2] * KVs[i * HD + d2];
        Sc[tt * CHK + i] = (i <= tt) ? sv : 0.0f;
    }
    __syncthreads();   // K fully consumed; Sc visible

    // den, and reload KVs with V
    if (tid < CHK) {
        float dv = 1e-6f;
        for (int d2 = 0; d2 < HD; ++d2) dv += Qc[tid * HD + d2] * zp[d2];
        for (int i = 0; i < CHK; ++i) dv += Sc[tid * CHK + i];   // masked entries are 0
        den[tid] = dv;
    }
    #pragma unroll
    for (int p = 0; p < 4; ++p) {
        int cc = p * 256 + tid;
        int t = cc >> 4, dp = (cc & 15) * 4;
        *(float4*)&KVs[t * HD + dp] = *(const float4*)(qkv + (size_t)(s0 + t) * QS + 2 * D + h * HD + dp);
    }
    __syncthreads();

    float o[16];
    #pragma unroll
    for (int j = 0; j < 16; ++j) o[j] = 0.0f;
    for (int d2 = 0; d2 < HD; ++d2) {
        float qv = Qc[tt * HD + d2];
        float sv = Sc[tt * CHK + d2];
        #pragma unroll
        for (int j = 0; j < 16; ++j)
            o[j] += qv * Pre[d2 * HD + i0 + j] + sv * KVs[d2 * HD + i0 + j];
    }
    const float inv = 1.0f / den[tt];
    unsigned short* op = attn + (size_t)(s0 + tt) * D + h * HD + i0;
    #pragma unroll
    for (int j0 = 0; j0 < 16; j0 += 4) {
        ushort4 ov = { f2bf(o[j0] * inv), f2bf(o[j0 + 1] * inv),
                       f2bf(o[j0 + 2] * inv), f2bf(o[j0 + 3] * inv) };
        *(ushort4*)(op + j0) = ov;
    }
}

// ---------------- launcher ----------------
extern "C" void kernel_launch(void* const* d_in, const int* in_sizes, int n_in,
                              void* d_out, int out_size, void* d_ws, size_t ws_size,
                              hipStream_t stream) {
    const float* x   = (const float*)d_in[0];
    const float* Wq  = (const float*)d_in[1];
    const float* bq  = (const float*)d_in[2];
    const float* Wk  = (const float*)d_in[3];
    const float* bk  = (const float*)d_in[4];
    const float* Wv  = (const float*)d_in[5];
    const float* bv  = (const float*)d_in[6];
    const float* Wo  = (const float*)d_in[7];
    const float* bo  = (const float*)d_in[8];
    const float* W1  = (const float*)d_in[9];
    const float* b1  = (const float*)d_in[10];
    const float* W2  = (const float*)d_in[11];
    const float* b2  = (const float*)d_in[12];
    const float* g1  = (const float*)d_in[13];
    const float* be1 = (const float*)d_in[14];
    const float* g2  = (const float*)d_in[15];
    const float* be2 = (const float*)d_in[16];
    float* out = (float*)d_out;

    char* wsp = (char*)d_ws;
    auto alloc = [&](size_t bytes) {
        char* p = wsp;
        wsp += (bytes + 255) & ~(size_t)255;
        return p;
    };
    // persistent buffers (total ~92 MB, within round-1's proven footprint)
    unsigned short* h1   = (unsigned short*)alloc((size_t)S * D * 2);   // LN1 out; reused as LN2 out
    unsigned short* attn = (unsigned short*)alloc((size_t)S * D * 2);
    unsigned short* gbuf = (unsigned short*)alloc((size_t)S * FF * 2);
    float* x2   = (float*)alloc((size_t)S * D * 4);
    unsigned short* Wqkvb = (unsigned short*)alloc((size_t)3 * D * D * 2);
    unsigned short* Wob   = (unsigned short*)alloc((size_t)D * D * 2);
    unsigned short* W1b   = (unsigned short*)alloc((size_t)FF * D * 2);
    unsigned short* W2b   = (unsigned short*)alloc((size_t)D * FF * 2);
    float* bqkv = (float*)alloc((size_t)3 * D * 4);
    float* KVc  = (float*)alloc((size_t)H * NC * HD * HD * 4);          // in-place prefix
    float* Zc   = (float*)alloc((size_t)H * NC * HD * 4);               // in-place prefix
    // union region: qkv (24 MB, dead after attn_out) / split-K partials (up to 32 MB)
    char* uni = (char*)alloc((size_t)32 * 1024 * 1024);
    float* qkv   = (float*)uni;          // S x (3*D) fp32
    float* parts = (float*)uni;          // up to 4 x S x D fp32

    const int DD4 = D * D / 4, FD4 = FF * D / 4;
    cvt_bf16<<<DD4 / 256, 256, 0, stream>>>(Wq, Wqkvb,             DD4);
    cvt_bf16<<<DD4 / 256, 256, 0, stream>>>(Wk, Wqkvb + D * D,     DD4);
    cvt_bf16<<<DD4 / 256, 256, 0, stream>>>(Wv, Wqkvb + 2 * D * D, DD4);
    cvt_bf16<<<DD4 / 256, 256, 0, stream>>>(Wo, Wob, DD4);
    cvt_bf16<<<FD4 / 256, 256, 0, stream>>>(W1, W1b, FD4);
    cvt_bf16<<<FD4 / 256, 256, 0, stream>>>(W2, W2b, FD4);
    concat3<<<(3 * D + 255) / 256, 256, 0, stream>>>(bq, bk, bv, bqkv);

    // LN1
    layernorm_bf16<<<S, 256, 0, stream>>>(x, g1, be1, h1);

    // fused QKV projection: M=2048, N=3072, K=1024 -> 384 blocks
    gemm_bt<EPI_QKV><<<dim3(S / 128, 3 * D / 128, 1), 256, 0, stream>>>(
        h1, Wqkvb, bqkv, qkv, S, 3 * D, D, 1);

    // chunked causal linear attention
    attn_chunk_sums<<<dim3(NC, H), 256, 0, stream>>>(qkv, KVc, Zc);
    attn_prefix<<<dim3(16, H), 256, 0, stream>>>(KVc, Zc);
    attn_out<<<dim3(NC, H), 256, 0, stream>>>(qkv, KVc, Zc, attn);

    // out-proj, split-K=2 -> 256 blocks; reduce adds bias + residual(x) -> x2
    gemm_bt<EPI_PART><<<dim3(S / 128, D / 128, 2), 256, 0, stream>>>(
        attn, Wob, nullptr, parts, S, D, D, 2);
    reduce_bias_res<<<(S * D / 4 + 255) / 256, 256, 0, stream>>>(
        parts, bo, x, x2, D / 4, S * D / 4, 2);

    // LN2 (h1 reused)
    layernorm_bf16<<<S, 256, 0, stream>>>(x2, g2, be2, h1);

    // FFN1: M=2048, N=4096, K=1024 -> 512 blocks, GELU fused, bf16 out
    gemm_bt<EPI_GELU_BF16><<<dim3(S / 128, FF / 128, 1), 256, 0, stream>>>(
        h1, W1b, b1, gbuf, S, FF, D, 1);

    // FFN2: split-K=4 -> 512 blocks; reduce adds bias + residual(x2) -> out
    gemm_bt<EPI_PART><<<dim3(S / 128, D / 128, 4), 256, 0, stream>>>(
        gbuf, W2b, nullptr, parts, S, D, FF, 4);
    reduce_bias_res<<<(S * D / 4 + 255) / 256, 256, 0, stream>>>(
        parts, b2, x2, out, D / 4, S * D / 4, 4);
}

// Round 3
// 291.559 us; speedup vs baseline: 1.4800x; 1.0957x over previous
//
#include <hip/hip_runtime.h>
#include <hip/hip_bf16.h>
#include <math.h>

// Problem constants (B=1)
constexpr int S  = 2048;
constexpr int D  = 1024;
constexpr int H  = 16;
constexpr int HD = 64;
constexpr int FF = 4096;
constexpr int NC  = 32;   // number of chunks for linear attention
constexpr int CHK = 64;   // chunk length (timesteps)
constexpr int QS  = 3 * D; // fused qkv row stride

typedef __attribute__((ext_vector_type(8))) short bf16x8;
typedef __attribute__((ext_vector_type(4))) float f32x4;

__device__ inline unsigned short f2bf(float f) {
    unsigned int u = __float_as_uint(f);
    u = (u + 0x7FFFu + ((u >> 16) & 1u)) >> 16;   // RNE
    return (unsigned short)u;
}

// ---------------- fused fp32 -> bf16 convert of ALL weights, one launch ----------------
// Segments (float4 units): Wq,Wk,Wv -> Wqkvb (concat), Wo -> Wob, W1 -> W1b, W2 -> W2b
constexpr int DD4 = D * D / 4;       // 262144
constexpr int FD4 = FF * D / 4;      // 1048576
constexpr int CVT_TOTAL4 = 4 * DD4 + 2 * FD4;   // 3145728

__global__ __launch_bounds__(256) void cvt6(const float* __restrict__ Wq,
                                            const float* __restrict__ Wk,
                                            const float* __restrict__ Wv,
                                            const float* __restrict__ Wo,
                                            const float* __restrict__ W1,
                                            const float* __restrict__ W2,
                                            unsigned short* __restrict__ Wqkvb,
                                            unsigned short* __restrict__ Wob,
                                            unsigned short* __restrict__ W1b,
                                            unsigned short* __restrict__ W2b) {
    int i = blockIdx.x * 256 + threadIdx.x;
    if (i >= CVT_TOTAL4) return;
    const float* s;
    unsigned short* dp;
    if (i < DD4)                 { s = Wq + (size_t)i * 4;               dp = Wqkvb + (size_t)i * 4; }
    else if (i < 2 * DD4)        { s = Wk + (size_t)(i - DD4) * 4;       dp = Wqkvb + (size_t)i * 4; }
    else if (i < 3 * DD4)        { s = Wv + (size_t)(i - 2 * DD4) * 4;   dp = Wqkvb + (size_t)i * 4; }
    else if (i < 4 * DD4)        { s = Wo + (size_t)(i - 3 * DD4) * 4;   dp = Wob + (size_t)(i - 3 * DD4) * 4; }
    else if (i < 4 * DD4 + FD4)  { s = W1 + (size_t)(i - 4 * DD4) * 4;   dp = W1b + (size_t)(i - 4 * DD4) * 4; }
    else                         { s = W2 + (size_t)(i - 4 * DD4 - FD4) * 4; dp = W2b + (size_t)(i - 4 * DD4 - FD4) * 4; }
    float4 v = *(const float4*)s;
    ushort4 o = { f2bf(v.x), f2bf(v.y), f2bf(v.z), f2bf(v.w) };
    *(ushort4*)dp = o;
}

// ---------------- LayerNorm (fp32 in, bf16 out), one block per row ----------------
__global__ __launch_bounds__(256) void layernorm_bf16(const float* __restrict__ x,
                                                      const float* __restrict__ g,
                                                      const float* __restrict__ b,
                                                      unsigned short* __restrict__ out) {
    const int row = blockIdx.x, tid = threadIdx.x;
    float4 v = ((const float4*)(x + (size_t)row * D))[tid];
    float s  = v.x + v.y + v.z + v.w;
    float ss = v.x*v.x + v.y*v.y + v.z*v.z + v.w*v.w;
    #pragma unroll
    for (int off = 32; off > 0; off >>= 1) {
        s  += __shfl_down(s, off);
        ss += __shfl_down(ss, off);
    }
    __shared__ float sw[4], ssw[4];
    if ((tid & 63) == 0) { sw[tid >> 6] = s; ssw[tid >> 6] = ss; }
    __syncthreads();
    s  = sw[0] + sw[1] + sw[2] + sw[3];
    ss = ssw[0] + ssw[1] + ssw[2] + ssw[3];
    const float mu = s * (1.0f / D);
    const float rs = rsqrtf(ss * (1.0f / D) - mu * mu + 1e-5f);
    float4 gv = ((const float4*)g)[tid];
    float4 bv = ((const float4*)b)[tid];
    ushort4 o = { f2bf((v.x - mu) * rs * gv.x + bv.x),
                  f2bf((v.y - mu) * rs * gv.y + bv.y),
                  f2bf((v.z - mu) * rs * gv.z + bv.z),
                  f2bf((v.w - mu) * rs * gv.w + bv.w) };
    ((ushort4*)(out + (size_t)row * D))[tid] = o;
}

// ---------------- split-K reduce fused with LayerNorm: x2 = sum part + bias + res; h = LN(x2) ----------------
template <int KS>
__global__ __launch_bounds__(256) void reduce_ln(const float* __restrict__ part,
                                                 const float* __restrict__ bias,
                                                 const float* __restrict__ res,
                                                 float* __restrict__ x2,
                                                 const float* __restrict__ g,
                                                 const float* __restrict__ b,
                                                 unsigned short* __restrict__ out) {
    const int row = blockIdx.x, tid = threadIdx.x;
    const size_t i4 = (size_t)row * 256 + tid;       // float4 index into SxD
    float4 a = ((const float4*)part)[i4];
    #pragma unroll
    for (int z = 1; z < KS; ++z) {
        float4 p = ((const float4*)part)[(size_t)z * S * 256 + i4];
        a.x += p.x; a.y += p.y; a.z += p.z; a.w += p.w;
    }
    float4 bi = ((const float4*)bias)[tid];
    float4 r  = ((const float4*)res)[i4];
    a.x += bi.x + r.x; a.y += bi.y + r.y; a.z += bi.z + r.z; a.w += bi.w + r.w;
    ((float4*)x2)[i4] = a;
    // LayerNorm of a
    float s  = a.x + a.y + a.z + a.w;
    float ss = a.x*a.x + a.y*a.y + a.z*a.z + a.w*a.w;
    #pragma unroll
    for (int off = 32; off > 0; off >>= 1) {
        s  += __shfl_down(s, off);
        ss += __shfl_down(ss, off);
    }
    __shared__ float sw[4], ssw[4];
    if ((tid & 63) == 0) { sw[tid >> 6] = s; ssw[tid >> 6] = ss; }
    __syncthreads();
    s  = sw[0] + sw[1] + sw[2] + sw[3];
    ss = ssw[0] + ssw[1] + ssw[2] + ssw[3];
    const float mu = s * (1.0f / D);
    const float rs = rsqrtf(ss * (1.0f / D) - mu * mu + 1e-5f);
    float4 gv = ((const float4*)g)[tid];
    float4 bv = ((const float4*)b)[tid];
    ushort4 o = { f2bf((a.x - mu) * rs * gv.x + bv.x),
                  f2bf((a.y - mu) * rs * gv.y + bv.y),
                  f2bf((a.z - mu) * rs * gv.z + bv.z),
                  f2bf((a.w - mu) * rs * gv.w + bv.w) };
    ((ushort4*)(out + (size_t)row * D))[tid] = o;
}

// ---------------- split-K reduce (final output, no LN) ----------------
template <int KS>
__global__ __launch_bounds__(256) void reduce_bias_res(const float* __restrict__ part,
                                                       const float* __restrict__ bias,
                                                       const float* __restrict__ res,
                                                       float* __restrict__ out,
                                                       int N4, int total4) {
    int i = blockIdx.x * 256 + threadIdx.x;
    if (i >= total4) return;
    float4 a = ((const float4*)part)[i];
    #pragma unroll
    for (int z = 1; z < KS; ++z) {
        float4 p = ((const float4*)part)[(size_t)z * total4 + i];
        a.x += p.x; a.y += p.y; a.z += p.z; a.w += p.w;
    }
    float4 b = ((const float4*)bias)[i % N4];
    float4 r = ((const float4*)res)[i];
    a.x += b.x + r.x; a.y += b.y + r.y; a.z += b.z + r.z; a.w += b.w + r.w;
    ((float4*)out)[i] = a;
}

// ---------------- bf16 MFMA GEMM: C = A (MxK) * W^T (W is NxK), m97-style staging ----------------
// 128x128 tile, BK=32, 512 threads = 8 waves in 2x4, each wave 64x32 (acc[4][2]).
// Rationale: same 16KB LDS + same grid as the 256-thr version, but 16 waves/CU at
// 2 blocks/CU -> barrier-drain of one block hidden by the other block's waves.
enum { EPI_F32 = 0, EPI_QKV = 1, EPI_GELU_BF16 = 2, EPI_PART = 3 };

template <int EPI>
__global__ __launch_bounds__(512, 4) void gemm_bt(const unsigned short* __restrict__ A,
                                                  const unsigned short* __restrict__ W,
                                                  const float* __restrict__ bias,
                                                  const float* __restrict__ bias2,
                                                  const float* __restrict__ bias3,
                                                  void* __restrict__ outp,
                                                  int M, int N, int K, int kSplit) {
    __shared__ unsigned short As[128 * 32];
    __shared__ unsigned short Bs[128 * 32];
    const int tid  = threadIdx.x;
    const int tileM = blockIdx.x * 128;
    const int tileN = blockIdx.y * 128;
    const int w    = tid >> 6, lane = tid & 63;
    const int wm   = (w >> 2) * 64, wn = (w & 3) * 32;
    const int lr   = lane & 15, lk = lane >> 4;
    const int kLen   = K / kSplit;
    const int kStart = blockIdx.z * kLen;
    const int kEnd   = kStart + kLen;
    const int srow = tid >> 2, skc = (tid & 3) * 8;   // staging: one 16B chunk per thread

    f32x4 acc[4][2];
    #pragma unroll
    for (int i = 0; i < 4; ++i)
        #pragma unroll
        for (int j = 0; j < 2; ++j) acc[i][j] = (f32x4)(0.0f);

    for (int k0 = kStart; k0 < kEnd; k0 += 32) {
        __builtin_amdgcn_global_load_lds(
            (const __attribute__((address_space(1))) unsigned int*)
                (A + (size_t)(tileM + srow) * K + k0 + skc),
            (__attribute__((address_space(3))) unsigned int*)&As[tid * 8],
            16, 0, 0);
        __builtin_amdgcn_global_load_lds(
            (const __attribute__((address_space(1))) unsigned int*)
                (W + (size_t)(tileN + srow) * K + k0 + skc),
            (__attribute__((address_space(3))) unsigned int*)&Bs[tid * 8],
            16, 0, 0);
        __syncthreads();
        bf16x8 af[4], bfv[2];
        #pragma unroll
        for (int i = 0; i < 4; ++i)
            af[i]  = *(const bf16x8*)&As[(wm + i * 16 + lr) * 32 + lk * 8];
        #pragma unroll
        for (int j = 0; j < 2; ++j)
            bfv[j] = *(const bf16x8*)&Bs[(wn + j * 16 + lr) * 32 + lk * 8];
        #pragma unroll
        for (int i = 0; i < 4; ++i)
            #pragma unroll
            for (int j = 0; j < 2; ++j)
                acc[i][j] = __builtin_amdgcn_mfma_f32_16x16x32_bf16(af[i], bfv[j], acc[i][j], 0, 0, 0);
        __syncthreads();
    }

    // Epilogue. C/D layout: col = lane&15, row = (lane>>4)*4 + reg   [m89/m91-verified]
    #pragma unroll
    for (int i = 0; i < 4; ++i) {
        const int rbase = tileM + wm + i * 16 + lk * 4;
        #pragma unroll
        for (int j = 0; j < 2; ++j) {
            const int col = tileN + wn + j * 16 + lr;
            #pragma unroll
            for (int r = 0; r < 4; ++r) {
                const int row = rbase + r;
                const size_t off = (size_t)row * N + col;
                float v = acc[i][j][r];
                if constexpr (EPI == EPI_PART) {
                    ((float*)outp)[(size_t)blockIdx.z * (size_t)M * (size_t)N + off] = v;
                } else if constexpr (EPI == EPI_QKV) {
                    // bias = bq, bias2 = bk, bias3 = bv; elu+1 on q,k columns
                    float bc = (col < D) ? bias[col] : ((col < 2 * D) ? bias2[col - D] : bias3[col - 2 * D]);
                    v += bc;
                    if (col < 2 * D) v = v > 0.0f ? v + 1.0f : __expf(v);
                    ((float*)outp)[off] = v;
                } else if constexpr (EPI == EPI_GELU_BF16) {
                    v += bias[col];
                    float gl = 0.5f * v * (1.0f + erff(v * 0.70710678118654752f));
                    ((unsigned short*)outp)[off] = f2bf(gl);
                } else {
                    v += bias[col];
                    ((float*)outp)[off] = v;
                }
            }
        }
    }
}

// ---------------- linear attention, chunked causal scan (fp32) ----------------
// qkv buffer layout: row s = [q(D) | k(D) | v(D)], stride QS=3*D.
__global__ __launch_bounds__(256) void attn_chunk_sums(const float* __restrict__ qkv,
                                                       float* __restrict__ KVc,
                                                       float* __restrict__ Zc) {
    const int c = blockIdx.x, h = blockIdx.y, tid = threadIdx.x;
    __shared__ float Kc[CHK * HD], Vc[CHK * HD];
    const int s0 = c * CHK;
    #pragma unroll
    for (int p = 0; p < 4; ++p) {
        int cc = p * 256 + tid;                 // 1024 float4 chunks
        int t = cc >> 4, dp = (cc & 15) * 4;
        *(float4*)&Kc[t * HD + dp] = *(const float4*)(qkv + (size_t)(s0 + t) * QS + D     + h * HD + dp);
        *(float4*)&Vc[t * HD + dp] = *(const float4*)(qkv + (size_t)(s0 + t) * QS + 2 * D + h * HD + dp);
    }
    __syncthreads();
    const int d = tid >> 2, e0 = (tid & 3) * 16;
    float acc[16];
    #pragma unroll
    for (int j = 0; j < 16; ++j) acc[j] = 0.0f;
    float zacc = 0.0f;
    for (int t = 0; t < CHK; ++t) {
        float kv = Kc[t * HD + d];
        zacc += kv;
        #pragma unroll
        for (int j = 0; j < 16; ++j) acc[j] += kv * Vc[t * HD + e0 + j];
    }
    float* op = KVc + ((size_t)(h * NC + c) * HD + d) * HD + e0;
    #pragma unroll
    for (int j = 0; j < 16; ++j) op[j] = acc[j];
    if ((tid & 3) == 0) Zc[(size_t)(h * NC + c) * HD + d] = zacc;
}

// exclusive prefix over chunks (per head), IN-PLACE (per-element chain)
__global__ __launch_bounds__(256) void attn_prefix(float* __restrict__ KVc,
                                                   float* __restrict__ Zc) {
    const int h = blockIdx.y;
    const int elem = blockIdx.x * 256 + threadIdx.x;      // 0..4095
    size_t base = (size_t)h * NC * (HD * HD) + elem;
    float run = 0.0f;
    for (int c = 0; c < NC; ++c) {
        float t = KVc[base + (size_t)c * (HD * HD)];
        KVc[base + (size_t)c * (HD * HD)] = run;
        run += t;
    }
    if (blockIdx.x == 0 && threadIdx.x < HD) {
        size_t zb = (size_t)h * NC * HD + threadIdx.x;
        float zr = 0.0f;
        for (int c = 0; c < NC; ++c) {
            float t = Zc[zb + (size_t)c * HD];
            Zc[zb + (size_t)c * HD] = zr;
            zr += t;
        }
    }
}

// out = (Q*KVpre + tril(QK^T)*V) / (Q.zpre + rowsum + eps)
__global__ __launch_bounds__(256) void attn_out(const float* __restrict__ qkv,
                                                const float* __restrict__ KVpre,
                                                const float* __restrict__ Zpre,
                                                unsigned short* __restrict__ attn) {
    const int c = blockIdx.x, h = blockIdx.y, tid = threadIdx.x;
    __shared__ float Qc[CHK * HD], KVs[CHK * HD], Pre[HD * HD], Sc[CHK * CHK];
    __shared__ float zp[HD], den[CHK];
    const int s0 = c * CHK;
    #pragma unroll
    for (int p = 0; p < 4; ++p) {
        int cc = p * 256 + tid;
        int t = cc >> 4, dp = (cc & 15) * 4;
        *(float4*)&Qc[t * HD + dp]  = *(const float4*)(qkv + (size_t)(s0 + t) * QS +     h * HD + dp);
        *(float4*)&KVs[t * HD + dp] = *(const float4*)(qkv + (size_t)(s0 + t) * QS + D + h * HD + dp);
        ((float4*)Pre)[cc] = *(const float4*)(KVpre + (size_t)(h * NC + c) * (HD * HD) + cc * 4);
    }
    if (tid < HD) zp[tid] = Zpre[(size_t)(h * NC + c) * HD + tid];
    __syncthreads();

    const int tt = tid >> 2, i0 = (tid & 3) * 16;
    // scores (masked)
    for (int i = i0; i < i0 + 16; ++i) {
        float sv = 0.0f;
        for (int d2 = 0; d2 < HD; ++d2) sv += Qc[tt * HD + d2] * KVs[i * HD + d2];
        Sc[tt * CHK + i] = (i <= tt) ? sv : 0.0f;
    }
    __syncthreads();   // K fully consumed; Sc visible

    // den, and reload KVs with V
    if (tid < CHK) {
        float dv = 1e-6f;
        for (int d2 = 0; d2 < HD; ++d2) dv += Qc[tid * HD + d2] * zp[d2];
        for (int i = 0; i < CHK; ++i) dv += Sc[tid * CHK + i];   // masked entries are 0
        den[tid] = dv;
    }
    #pragma unroll
    for (int p = 0; p < 4; ++p) {
        int cc = p * 256 + tid;
        int t = cc >> 4, dp = (cc & 15) * 4;
        *(float4*)&KVs[t * HD + dp] = *(const float4*)(qkv + (size_t)(s0 + t) * QS + 2 * D + h * HD + dp);
    }
    __syncthreads();

    float o[16];
    #pragma unroll
    for (int j = 0; j < 16; ++j) o[j] = 0.0f;
    for (int d2 = 0; d2 < HD; ++d2) {
        float qv = Qc[tt * HD + d2];
        float sv = Sc[tt * CHK + d2];
        #pragma unroll
        for (int j = 0; j < 16; ++j)
            o[j] += qv * Pre[d2 * HD + i0 + j] + sv * KVs[d2 * HD + i0 + j];
    }
    const float inv = 1.0f / den[tt];
    unsigned short* op = attn + (size_t)(s0 + tt) * D + h * HD + i0;
    #pragma unroll
    for (int j0 = 0; j0 < 16; j0 += 4) {
        ushort4 ov = { f2bf(o[j0] * inv), f2bf(o[j0 + 1] * inv),
                       f2bf(o[j0 + 2] * inv), f2bf(o[j0 + 3] * inv) };
        *(ushort4*)(op + j0) = ov;
    }
}

// ---------------- launcher ----------------
extern "C" void kernel_launch(void* const* d_in, const int* in_sizes, int n_in,
                              void* d_out, int out_size, void* d_ws, size_t ws_size,
                              hipStream_t stream) {
    const float* x   = (const float*)d_in[0];
    const float* Wq  = (const float*)d_in[1];
    const float* bq  = (const float*)d_in[2];
    const float* Wk  = (const float*)d_in[3];
    const float* bk  = (const float*)d_in[4];
    const float* Wv  = (const float*)d_in[5];
    const float* bv  = (const float*)d_in[6];
    const float* Wo  = (const float*)d_in[7];
    const float* bo  = (const float*)d_in[8];
    const float* W1  = (const float*)d_in[9];
    const float* b1  = (const float*)d_in[10];
    const float* W2  = (const float*)d_in[11];
    const float* b2  = (const float*)d_in[12];
    const float* g1  = (const float*)d_in[13];
    const float* be1 = (const float*)d_in[14];
    const float* g2  = (const float*)d_in[15];
    const float* be2 = (const float*)d_in[16];
    float* out = (float*)d_out;

    char* wsp = (char*)d_ws;
    auto alloc = [&](size_t bytes) {
        char* p = wsp;
        wsp += (bytes + 255) & ~(size_t)255;
        return p;
    };
    unsigned short* h1   = (unsigned short*)alloc((size_t)S * D * 2);   // LN1 out; reused as LN2 out
    unsigned short* attn = (unsigned short*)alloc((size_t)S * D * 2);
    unsigned short* gbuf = (unsigned short*)alloc((size_t)S * FF * 2);
    float* x2   = (float*)alloc((size_t)S * D * 4);
    unsigned short* Wqkvb = (unsigned short*)alloc((size_t)3 * D * D * 2);
    unsigned short* Wob   = (unsigned short*)alloc((size_t)D * D * 2);
    unsigned short* W1b   = (unsigned short*)alloc((size_t)FF * D * 2);
    unsigned short* W2b   = (unsigned short*)alloc((size_t)D * FF * 2);
    float* KVc  = (float*)alloc((size_t)H * NC * HD * HD * 4);          // in-place prefix
    float* Zc   = (float*)alloc((size_t)H * NC * HD * 4);               // in-place prefix
    // union region: qkv (24 MB, dead after attn_out) / split-K partials (up to 32 MB)
    char* uni = (char*)alloc((size_t)32 * 1024 * 1024);
    float* qkv   = (float*)uni;          // S x (3*D) fp32
    float* parts = (float*)uni;          // up to 4 x S x D fp32

    // all weight conversions in one launch
    cvt6<<<(CVT_TOTAL4 + 255) / 256, 256, 0, stream>>>(Wq, Wk, Wv, Wo, W1, W2,
                                                       Wqkvb, Wob, W1b, W2b);

    // LN1
    layernorm_bf16<<<S, 256, 0, stream>>>(x, g1, be1, h1);

    // fused QKV projection: M=2048, N=3072, K=1024 -> 384 blocks x 8 waves
    gemm_bt<EPI_QKV><<<dim3(S / 128, 3 * D / 128, 1), 512, 0, stream>>>(
        h1, Wqkvb, bq, bk, bv, qkv, S, 3 * D, D, 1);

    // chunked causal linear attention
    attn_chunk_sums<<<dim3(NC, H), 256, 0, stream>>>(qkv, KVc, Zc);
    attn_prefix<<<dim3(16, H), 256, 0, stream>>>(KVc, Zc);
    attn_out<<<dim3(NC, H), 256, 0, stream>>>(qkv, KVc, Zc, attn);

    // out-proj, split-K=2 -> 256 blocks; fused reduce+bias+residual(x)+LN2 -> x2, h1
    gemm_bt<EPI_PART><<<dim3(S / 128, D / 128, 2), 512, 0, stream>>>(
        attn, Wob, nullptr, nullptr, nullptr, parts, S, D, D, 2);
    reduce_ln<2><<<S, 256, 0, stream>>>(parts, bo, x, x2, g2, be2, h1);

    // FFN1: M=2048, N=4096, K=1024 -> 512 blocks, GELU fused, bf16 out
    gemm_bt<EPI_GELU_BF16><<<dim3(S / 128, FF / 128, 1), 512, 0, stream>>>(
        h1, W1b, b1, nullptr, nullptr, gbuf, S, FF, D, 1);

    // FFN2: split-K=4 -> 512 blocks; reduce adds bias + residual(x2) -> out
    gemm_bt<EPI_PART><<<dim3(S / 128, D / 128, 4), 512, 0, stream>>>(
        gbuf, W2b, nullptr, nullptr, nullptr, parts, S, D, FF, 4);
    reduce_bias_res<4><<<(S * D / 4 + 255) / 256, 256, 0, stream>>>(
        parts, b2, x2, out, D / 4, S * D / 4);
}

// Round 4
// 280.349 us; speedup vs baseline: 1.5392x; 1.0400x over previous
//
#include <hip/hip_runtime.h>
#include <hip/hip_bf16.h>
#include <math.h>

// Problem constants (B=1)
constexpr int S  = 2048;
constexpr int D  = 1024;
constexpr int H  = 16;
constexpr int HD = 64;
constexpr int FF = 4096;
constexpr int NC  = 32;   // number of chunks for linear attention
constexpr int CHK = 64;   // chunk length (timesteps)
constexpr int QS  = 3 * D; // fused qkv row stride

typedef __attribute__((ext_vector_type(8))) short bf16x8;
typedef __attribute__((ext_vector_type(4))) float f32x4;

__device__ inline unsigned short f2bf(float f) {
    unsigned int u = __float_as_uint(f);
    u = (u + 0x7FFFu + ((u >> 16) & 1u)) >> 16;   // RNE
    return (unsigned short)u;
}

// ---------------- fused fp32 -> bf16 convert of ALL weights, one launch ----------------
constexpr int DD4 = D * D / 4;       // 262144
constexpr int FD4 = FF * D / 4;      // 1048576
constexpr int CVT_TOTAL4 = 4 * DD4 + 2 * FD4;   // 3145728

__global__ __launch_bounds__(256) void cvt6(const float* __restrict__ Wq,
                                            const float* __restrict__ Wk,
                                            const float* __restrict__ Wv,
                                            const float* __restrict__ Wo,
                                            const float* __restrict__ W1,
                                            const float* __restrict__ W2,
                                            unsigned short* __restrict__ Wqkvb,
                                            unsigned short* __restrict__ Wob,
                                            unsigned short* __restrict__ W1b,
                                            unsigned short* __restrict__ W2b) {
    int i = blockIdx.x * 256 + threadIdx.x;
    if (i >= CVT_TOTAL4) return;
    const float* s;
    unsigned short* dp;
    if (i < DD4)                 { s = Wq + (size_t)i * 4;               dp = Wqkvb + (size_t)i * 4; }
    else if (i < 2 * DD4)        { s = Wk + (size_t)(i - DD4) * 4;       dp = Wqkvb + (size_t)i * 4; }
    else if (i < 3 * DD4)        { s = Wv + (size_t)(i - 2 * DD4) * 4;   dp = Wqkvb + (size_t)i * 4; }
    else if (i < 4 * DD4)        { s = Wo + (size_t)(i - 3 * DD4) * 4;   dp = Wob + (size_t)(i - 3 * DD4) * 4; }
    else if (i < 4 * DD4 + FD4)  { s = W1 + (size_t)(i - 4 * DD4) * 4;   dp = W1b + (size_t)(i - 4 * DD4) * 4; }
    else                         { s = W2 + (size_t)(i - 4 * DD4 - FD4) * 4; dp = W2b + (size_t)(i - 4 * DD4 - FD4) * 4; }
    float4 v = *(const float4*)s;
    ushort4 o = { f2bf(v.x), f2bf(v.y), f2bf(v.z), f2bf(v.w) };
    *(ushort4*)dp = o;
}

// ---------------- LayerNorm (fp32 in, bf16 out), one block per row ----------------
__global__ __launch_bounds__(256) void layernorm_bf16(const float* __restrict__ x,
                                                      const float* __restrict__ g,
                                                      const float* __restrict__ b,
                                                      unsigned short* __restrict__ out) {
    const int row = blockIdx.x, tid = threadIdx.x;
    float4 v = ((const float4*)(x + (size_t)row * D))[tid];
    float s  = v.x + v.y + v.z + v.w;
    float ss = v.x*v.x + v.y*v.y + v.z*v.z + v.w*v.w;
    #pragma unroll
    for (int off = 32; off > 0; off >>= 1) {
        s  += __shfl_down(s, off);
        ss += __shfl_down(ss, off);
    }
    __shared__ float sw[4], ssw[4];
    if ((tid & 63) == 0) { sw[tid >> 6] = s; ssw[tid >> 6] = ss; }
    __syncthreads();
    s  = sw[0] + sw[1] + sw[2] + sw[3];
    ss = ssw[0] + ssw[1] + ssw[2] + ssw[3];
    const float mu = s * (1.0f / D);
    const float rs = rsqrtf(ss * (1.0f / D) - mu * mu + 1e-5f);
    float4 gv = ((const float4*)g)[tid];
    float4 bv = ((const float4*)b)[tid];
    ushort4 o = { f2bf((v.x - mu) * rs * gv.x + bv.x),
                  f2bf((v.y - mu) * rs * gv.y + bv.y),
                  f2bf((v.z - mu) * rs * gv.z + bv.z),
                  f2bf((v.w - mu) * rs * gv.w + bv.w) };
    ((ushort4*)(out + (size_t)row * D))[tid] = o;
}

// ---------------- split-K reduce fused with LayerNorm ----------------
template <int KS>
__global__ __launch_bounds__(256) void reduce_ln(const float* __restrict__ part,
                                                 const float* __restrict__ bias,
                                                 const float* __restrict__ res,
                                                 float* __restrict__ x2,
                                                 const float* __restrict__ g,
                                                 const float* __restrict__ b,
                                                 unsigned short* __restrict__ out) {
    const int row = blockIdx.x, tid = threadIdx.x;
    const size_t i4 = (size_t)row * 256 + tid;       // float4 index into SxD
    float4 a = ((const float4*)part)[i4];
    #pragma unroll
    for (int z = 1; z < KS; ++z) {
        float4 p = ((const float4*)part)[(size_t)z * S * 256 + i4];
        a.x += p.x; a.y += p.y; a.z += p.z; a.w += p.w;
    }
    float4 bi = ((const float4*)bias)[tid];
    float4 r  = ((const float4*)res)[i4];
    a.x += bi.x + r.x; a.y += bi.y + r.y; a.z += bi.z + r.z; a.w += bi.w + r.w;
    ((float4*)x2)[i4] = a;
    float s  = a.x + a.y + a.z + a.w;
    float ss = a.x*a.x + a.y*a.y + a.z*a.z + a.w*a.w;
    #pragma unroll
    for (int off = 32; off > 0; off >>= 1) {
        s  += __shfl_down(s, off);
        ss += __shfl_down(ss, off);
    }
    __shared__ float sw[4], ssw[4];
    if ((tid & 63) == 0) { sw[tid >> 6] = s; ssw[tid >> 6] = ss; }
    __syncthreads();
    s  = sw[0] + sw[1] + sw[2] + sw[3];
    ss = ssw[0] + ssw[1] + ssw[2] + ssw[3];
    const float mu = s * (1.0f / D);
    const float rs = rsqrtf(ss * (1.0f / D) - mu * mu + 1e-5f);
    float4 gv = ((const float4*)g)[tid];
    float4 bv = ((const float4*)b)[tid];
    ushort4 o = { f2bf((a.x - mu) * rs * gv.x + bv.x),
                  f2bf((a.y - mu) * rs * gv.y + bv.y),
                  f2bf((a.z - mu) * rs * gv.z + bv.z),
                  f2bf((a.w - mu) * rs * gv.w + bv.w) };
    ((ushort4*)(out + (size_t)row * D))[tid] = o;
}

// ---------------- split-K reduce (final output, no LN) ----------------
template <int KS>
__global__ __launch_bounds__(256) void reduce_bias_res(const float* __restrict__ part,
                                                       const float* __restrict__ bias,
                                                       const float* __restrict__ res,
                                                       float* __restrict__ out,
                                                       int N4, int total4) {
    int i = blockIdx.x * 256 + threadIdx.x;
    if (i >= total4) return;
    float4 a = ((const float4*)part)[i];
    #pragma unroll
    for (int z = 1; z < KS; ++z) {
        float4 p = ((const float4*)part)[(size_t)z * total4 + i];
        a.x += p.x; a.y += p.y; a.z += p.z; a.w += p.w;
    }
    float4 b = ((const float4*)bias)[i % N4];
    float4 r = ((const float4*)res)[i];
    a.x += b.x + r.x; a.y += b.y + r.y; a.z += b.z + r.z; a.w += b.w + r.w;
    ((float4*)out)[i] = a;
}

// ---------------- bf16 MFMA GEMM: C = A (MxK) * W^T (W is NxK) ----------------
// 128x128 tile, BK=64, 256 threads (4 waves 2x2, 64x64 wave tiles, 4x4 acc).
// Ping-pong LDS double buffer (64 KB), ONE barrier per K-step: prefetch for step
// k+1 is issued right after the barrier, so the compiler's vmcnt(0) drain at the
// next barrier waits on loads that already had a full compute phase to land.
// XOR-swizzled LDS layout: chunk (row,kc) at row*128B + (kc ^ ((row>>1)&7))*16B.
// Swizzle applied to the GLOBAL source index, so the LDS write side stays linear
// in lane order (required by global_load_lds wave-uniform-base semantics) and
// staging stays 128B-coalesced. Fragment-read phases then hit each 4-bank group
// exactly twice -> 2-way = free (m136).
enum { EPI_F32 = 0, EPI_QKV = 1, EPI_GELU_BF16 = 2, EPI_PART = 3 };

template <int EPI>
__global__ __launch_bounds__(256, 2) void gemm_bt(const unsigned short* __restrict__ A,
                                                  const unsigned short* __restrict__ W,
                                                  const float* __restrict__ bias,
                                                  const float* __restrict__ bias2,
                                                  const float* __restrict__ bias3,
                                                  void* __restrict__ outp,
                                                  int M, int N, int K, int kSplit) {
    __shared__ unsigned short As[2][128 * 64];
    __shared__ unsigned short Bs[2][128 * 64];
    const int tid  = threadIdx.x;
    const int tileM = blockIdx.x * 128;
    const int tileN = blockIdx.y * 128;
    const int w    = tid >> 6, lane = tid & 63;
    const int wm   = (w >> 1) * 64, wn = (w & 1) * 64;
    const int lr   = lane & 15, lk = lane >> 4;
    const int sw   = (lr >> 1) & 7;                    // fragment-read swizzle (lane const)
    const int kLen   = K / kSplit;
    const int kStart = blockIdx.z * kLen;
    const int kEnd   = kStart + kLen;

    f32x4 acc[4][4];
    #pragma unroll
    for (int i = 0; i < 4; ++i)
        #pragma unroll
        for (int j = 0; j < 4; ++j) acc[i][j] = (f32x4)(0.0f);

    // stage one BK=64 tile pair into buffer `buf`
    auto stage = [&](int buf, int k0) {
        #pragma unroll
        for (int p = 0; p < 4; ++p) {
            const int c   = p * 256 + tid;            // 1024 chunks of 16B per tile
            const int row = c >> 3;
            const int kc  = (c & 7) ^ ((row >> 1) & 7);   // swizzled global source
            __builtin_amdgcn_global_load_lds(
                (const __attribute__((address_space(1))) unsigned int*)
                    (A + (size_t)(tileM + row) * K + k0 + kc * 8),
                (__attribute__((address_space(3))) unsigned int*)&As[buf][c * 8],
                16, 0, 0);
            __builtin_amdgcn_global_load_lds(
                (const __attribute__((address_space(1))) unsigned int*)
                    (W + (size_t)(tileN + row) * K + k0 + kc * 8),
                (__attribute__((address_space(3))) unsigned int*)&Bs[buf][c * 8],
                16, 0, 0);
        }
    };

    stage(0, kStart);
    __syncthreads();                                   // prologue drain (once)
    int buf = 0;
    for (int k0 = kStart; k0 < kEnd; k0 += 64) {
        if (k0 + 64 < kEnd) stage(buf ^ 1, k0 + 64);   // prefetch overlaps compute below
        #pragma unroll
        for (int kk = 0; kk < 2; ++kk) {
            bf16x8 af[4], bfv[4];
            #pragma unroll
            for (int i = 0; i < 4; ++i) {
                const int row = wm + i * 16 + lr;
                af[i] = *(const bf16x8*)&As[buf][row * 64 + ((((kk << 2) | lk) ^ sw) << 3)];
            }
            #pragma unroll
            for (int j = 0; j < 4; ++j) {
                const int row = wn + j * 16 + lr;
                bfv[j] = *(const bf16x8*)&Bs[buf][row * 64 + ((((kk << 2) | lk) ^ sw) << 3)];
            }
            #pragma unroll
            for (int i = 0; i < 4; ++i)
                #pragma unroll
                for (int j = 0; j < 4; ++j)
                    acc[i][j] = __builtin_amdgcn_mfma_f32_16x16x32_bf16(af[i], bfv[j], acc[i][j], 0, 0, 0);
        }
        __syncthreads();   // drains prefetch (mostly landed) + guards buf reuse
        buf ^= 1;
    }

    // Epilogue. C/D layout: col = lane&15, row = (lane>>4)*4 + reg   [m89/m91-verified]
    #pragma unroll
    for (int i = 0; i < 4; ++i) {
        const int rbase = tileM + wm + i * 16 + lk * 4;
        #pragma unroll
        for (int j = 0; j < 4; ++j) {
            const int col = tileN + wn + j * 16 + lr;
            #pragma unroll
            for (int r = 0; r < 4; ++r) {
                const int row = rbase + r;
                const size_t off = (size_t)row * N + col;
                float v = acc[i][j][r];
                if constexpr (EPI == EPI_PART) {
                    ((float*)outp)[(size_t)blockIdx.z * (size_t)M * (size_t)N + off] = v;
                } else if constexpr (EPI == EPI_QKV) {
                    float bc = (col < D) ? bias[col] : ((col < 2 * D) ? bias2[col - D] : bias3[col - 2 * D]);
                    v += bc;
                    if (col < 2 * D) v = v > 0.0f ? v + 1.0f : __expf(v);
                    ((float*)outp)[off] = v;
                } else if constexpr (EPI == EPI_GELU_BF16) {
                    v += bias[col];
                    float gl = 0.5f * v * (1.0f + erff(v * 0.70710678118654752f));
                    ((unsigned short*)outp)[off] = f2bf(gl);
                } else {
                    v += bias[col];
                    ((float*)outp)[off] = v;
                }
            }
        }
    }
}

// ---------------- linear attention, chunked causal scan (fp32) ----------------
__global__ __launch_bounds__(256) void attn_chunk_sums(const float* __restrict__ qkv,
                                                       float* __restrict__ KVc,
                                                       float* __restrict__ Zc) {
    const int c = blockIdx.x, h = blockIdx.y, tid = threadIdx.x;
    __shared__ float Kc[CHK * HD], Vc[CHK * HD];
    const int s0 = c * CHK;
    #pragma unroll
    for (int p = 0; p < 4; ++p) {
        int cc = p * 256 + tid;
        int t = cc >> 4, dp = (cc & 15) * 4;
        *(float4*)&Kc[t * HD + dp] = *(const float4*)(qkv + (size_t)(s0 + t) * QS + D     + h * HD + dp);
        *(float4*)&Vc[t * HD + dp] = *(const float4*)(qkv + (size_t)(s0 + t) * QS + 2 * D + h * HD + dp);
    }
    __syncthreads();
    const int d = tid >> 2, e0 = (tid & 3) * 16;
    float acc[16];
    #pragma unroll
    for (int j = 0; j < 16; ++j) acc[j] = 0.0f;
    float zacc = 0.0f;
    for (int t = 0; t < CHK; ++t) {
        float kv = Kc[t * HD + d];
        zacc += kv;
        #pragma unroll
        for (int j = 0; j < 16; ++j) acc[j] += kv * Vc[t * HD + e0 + j];
    }
    float* op = KVc + ((size_t)(h * NC + c) * HD + d) * HD + e0;
    #pragma unroll
    for (int j = 0; j < 16; ++j) op[j] = acc[j];
    if ((tid & 3) == 0) Zc[(size_t)(h * NC + c) * HD + d] = zacc;
}

__global__ __launch_bounds__(256) void attn_prefix(float* __restrict__ KVc,
                                                   float* __restrict__ Zc) {
    const int h = blockIdx.y;
    const int elem = blockIdx.x * 256 + threadIdx.x;
    size_t base = (size_t)h * NC * (HD * HD) + elem;
    float run = 0.0f;
    for (int c = 0; c < NC; ++c) {
        float t = KVc[base + (size_t)c * (HD * HD)];
        KVc[base + (size_t)c * (HD * HD)] = run;
        run += t;
    }
    if (blockIdx.x == 0 && threadIdx.x < HD) {
        size_t zb = (size_t)h * NC * HD + threadIdx.x;
        float zr = 0.0f;
        for (int c = 0; c < NC; ++c) {
            float t = Zc[zb + (size_t)c * HD];
            Zc[zb + (size_t)c * HD] = zr;
            zr += t;
        }
    }
}

__global__ __launch_bounds__(256) void attn_out(const float* __restrict__ qkv,
                                                const float* __restrict__ KVpre,
                                                const float* __restrict__ Zpre,
                                                unsigned short* __restrict__ attn) {
    const int c = blockIdx.x, h = blockIdx.y, tid = threadIdx.x;
    __shared__ float Qc[CHK * HD], KVs[CHK * HD], Pre[HD * HD], Sc[CHK * CHK];
    __shared__ float zp[HD], den[CHK];
    const int s0 = c * CHK;
    #pragma unroll
    for (int p = 0; p < 4; ++p) {
        int cc = p * 256 + tid;
        int t = cc >> 4, dp = (cc & 15) * 4;
        *(float4*)&Qc[t * HD + dp]  = *(const float4*)(qkv + (size_t)(s0 + t) * QS +     h * HD + dp);
        *(float4*)&KVs[t * HD + dp] = *(const float4*)(qkv + (size_t)(s0 + t) * QS + D + h * HD + dp);
        ((float4*)Pre)[cc] = *(const float4*)(KVpre + (size_t)(h * NC + c) * (HD * HD) + cc * 4);
    }
    if (tid < HD) zp[tid] = Zpre[(size_t)(h * NC + c) * HD + tid];
    __syncthreads();

    const int tt = tid >> 2, i0 = (tid & 3) * 16;
    for (int i = i0; i < i0 + 16; ++i) {
        float sv = 0.0f;
        for (int d2 = 0; d2 < HD; ++d2) sv += Qc[tt * HD + d2] * KVs[i * HD + d2];
        Sc[tt * CHK + i] = (i <= tt) ? sv : 0.0f;
    }
    __syncthreads();

    if (tid < CHK) {
        float dv = 1e-6f;
        for (int d2 = 0; d2 < HD; ++d2) dv += Qc[tid * HD + d2] * zp[d2];
        for (int i = 0; i < CHK; ++i) dv += Sc[tid * CHK + i];
        den[tid] = dv;
    }
    #pragma unroll
    for (int p = 0; p < 4; ++p) {
        int cc = p * 256 + tid;
        int t = cc >> 4, dp = (cc & 15) * 4;
        *(float4*)&KVs[t * HD + dp] = *(const float4*)(qkv + (size_t)(s0 + t) * QS + 2 * D + h * HD + dp);
    }
    __syncthreads();

    float o[16];
    #pragma unroll
    for (int j = 0; j < 16; ++j) o[j] = 0.0f;
    for (int d2 = 0; d2 < HD; ++d2) {
        float qv = Qc[tt * HD + d2];
        float sv = Sc[tt * CHK + d2];
        #pragma unroll
        for (int j = 0; j < 16; ++j)
            o[j] += qv * Pre[d2 * HD + i0 + j] + sv * KVs[d2 * HD + i0 + j];
    }
    const float inv = 1.0f / den[tt];
    unsigned short* op = attn + (size_t)(s0 + tt) * D + h * HD + i0;
    #pragma unroll
    for (int j0 = 0; j0 < 16; j0 += 4) {
        ushort4 ov = { f2bf(o[j0] * inv), f2bf(o[j0 + 1] * inv),
                       f2bf(o[j0 + 2] * inv), f2bf(o[j0 + 3] * inv) };
        *(ushort4*)(op + j0) = ov;
    }
}

// ---------------- launcher ----------------
extern "C" void kernel_launch(void* const* d_in, const int* in_sizes, int n_in,
                              void* d_out, int out_size, void* d_ws, size_t ws_size,
                              hipStream_t stream) {
    const float* x   = (const float*)d_in[0];
    const float* Wq  = (const float*)d_in[1];
    const float* bq  = (const float*)d_in[2];
    const float* Wk  = (const float*)d_in[3];
    const float* bk  = (const float*)d_in[4];
    const float* Wv  = (const float*)d_in[5];
    const float* bv  = (const float*)d_in[6];
    const float* Wo  = (const float*)d_in[7];
    const float* bo  = (const float*)d_in[8];
    const float* W1  = (const float*)d_in[9];
    const float* b1  = (const float*)d_in[10];
    const float* W2  = (const float*)d_in[11];
    const float* b2  = (const float*)d_in[12];
    const float* g1  = (const float*)d_in[13];
    const float* be1 = (const float*)d_in[14];
    const float* g2  = (const float*)d_in[15];
    const float* be2 = (const float*)d_in[16];
    float* out = (float*)d_out;

    char* wsp = (char*)d_ws;
    auto alloc = [&](size_t bytes) {
        char* p = wsp;
        wsp += (bytes + 255) & ~(size_t)255;
        return p;
    };
    unsigned short* h1   = (unsigned short*)alloc((size_t)S * D * 2);   // LN1 out; reused as LN2 out
    unsigned short* attn = (unsigned short*)alloc((size_t)S * D * 2);
    unsigned short* gbuf = (unsigned short*)alloc((size_t)S * FF * 2);
    float* x2   = (float*)alloc((size_t)S * D * 4);
    unsigned short* Wqkvb = (unsigned short*)alloc((size_t)3 * D * D * 2);
    unsigned short* Wob   = (unsigned short*)alloc((size_t)D * D * 2);
    unsigned short* W1b   = (unsigned short*)alloc((size_t)FF * D * 2);
    unsigned short* W2b   = (unsigned short*)alloc((size_t)D * FF * 2);
    float* KVc  = (float*)alloc((size_t)H * NC * HD * HD * 4);          // in-place prefix
    float* Zc   = (float*)alloc((size_t)H * NC * HD * 4);               // in-place prefix
    // union region: qkv (24 MB, dead after attn_out) / split-K partials (32 MB)
    char* uni = (char*)alloc((size_t)32 * 1024 * 1024);
    float* qkv   = (float*)uni;          // S x (3*D) fp32
    float* parts = (float*)uni;          // up to 4 x S x D fp32

    cvt6<<<(CVT_TOTAL4 + 255) / 256, 256, 0, stream>>>(Wq, Wk, Wv, Wo, W1, W2,
                                                       Wqkvb, Wob, W1b, W2b);

    // LN1
    layernorm_bf16<<<S, 256, 0, stream>>>(x, g1, be1, h1);

    // fused QKV projection: M=2048, N=3072, K=1024 -> 384 blocks
    gemm_bt<EPI_QKV><<<dim3(S / 128, 3 * D / 128, 1), 256, 0, stream>>>(
        h1, Wqkvb, bq, bk, bv, qkv, S, 3 * D, D, 1);

    // chunked causal linear attention
    attn_chunk_sums<<<dim3(NC, H), 256, 0, stream>>>(qkv, KVc, Zc);
    attn_prefix<<<dim3(16, H), 256, 0, stream>>>(KVc, Zc);
    attn_out<<<dim3(NC, H), 256, 0, stream>>>(qkv, KVc, Zc, attn);

    // out-proj, split-K=4 -> 512 blocks; fused reduce+bias+residual(x)+LN2
    gemm_bt<EPI_PART><<<dim3(S / 128, D / 128, 4), 256, 0, stream>>>(
        attn, Wob, nullptr, nullptr, nullptr, parts, S, D, D, 4);
    reduce_ln<4><<<S, 256, 0, stream>>>(parts, bo, x, x2, g2, be2, h1);

    // FFN1: M=2048, N=4096, K=1024 -> 512 blocks, GELU fused, bf16 out
    gemm_bt<EPI_GELU_BF16><<<dim3(S / 128, FF / 128, 1), 256, 0, stream>>>(
        h1, W1b, b1, nullptr, nullptr, gbuf, S, FF, D, 1);

    // FFN2: split-K=4 -> 512 blocks; reduce adds bias + residual(x2) -> out
    gemm_bt<EPI_PART><<<dim3(S / 128, D / 128, 4), 256, 0, stream>>>(
        gbuf, W2b, nullptr, nullptr, nullptr, parts, S, D, FF, 4);
    reduce_bias_res<4><<<(S * D / 4 + 255) / 256, 256, 0, stream>>>(
        parts, b2, x2, out, D / 4, S * D / 4);
}